// Round 5
// baseline (461.674 us; speedup 1.0000x reference)
//
#include <hip/hip_runtime.h>
#include <math.h>

#define D_NODE 100
#define D_HID  300
static const int TSEQ = 512, LQn = 256, NNODE = 256;

typedef unsigned int u32;
typedef unsigned short u16;
typedef __attribute__((ext_vector_type(8))) short bf16x8;   // 8 bf16 = 4 VGPRs
typedef __attribute__((ext_vector_type(4))) float f32x4;

__device__ __forceinline__ float bflo(u32 u){ return __uint_as_float(u << 16); }
__device__ __forceinline__ float bfhi(u32 u){ return __uint_as_float(u & 0xffff0000u); }
__device__ __forceinline__ float bf2f(u16 v){ return __uint_as_float(((u32)v) << 16); }
__device__ __forceinline__ u16 f2bf(float f){
    u32 u = __float_as_uint(f);
    return (u16)((u + 0x7fffu + ((u >> 16) & 1u)) >> 16);
}
__device__ __forceinline__ u32 pack_bf(float lo, float hi){
    return ((u32)f2bf(lo)) | (((u32)f2bf(hi)) << 16);
}
__device__ __forceinline__ void gload_lds16(const void* g, void* l){
    __builtin_amdgcn_global_load_lds(
        (const __attribute__((address_space(1))) u32*)g,
        (__attribute__((address_space(3))) u32*)l, 16, 0, 0);
}
__device__ __forceinline__ float fsig(float x){
    return __builtin_amdgcn_rcpf(1.f + __expf(-x));
}
__device__ __forceinline__ float ftanh(float x){
    return 1.f - 2.f*__builtin_amdgcn_rcpf(1.f + __expf(2.f*x));
}

// ---------------- K0: fold W_mean into GRU weights -> W4bf bf16 [dir][gate][320 j][128 k] ----------------
__global__ __launch_bounds__(128)
void k0_prep(const float* __restrict__ Wm, const float* __restrict__ bm,
             const float* __restrict__ Wihf, const float* __restrict__ bihf, const float* __restrict__ bhhf,
             const float* __restrict__ Wihb, const float* __restrict__ bihb, const float* __restrict__ bhhb,
             u16* __restrict__ W4bf, float* __restrict__ bc, float* __restrict__ bhhn)
{
    int j = blockIdx.x, g = blockIdx.y, dir = blockIdx.z;
    int tid = threadIdx.x;
    u16* wout = W4bf + ((size_t)((dir*3+g)*320 + j))*128;
    if (j >= D_HID) {
        wout[tid] = 0;
        if (tid == 0) { bc[(dir*3+g)*320 + j] = 0.f; if (g==2) bhhn[dir*320+j] = 0.f; }
        return;
    }
    const float* Wih = dir ? Wihb : Wihf;
    const float* bih = dir ? bihb : bihf;
    const float* bhh = dir ? bhhb : bhhf;
    const float* wrow = Wih + (size_t)(g*D_HID + j)*D_HID;
    int k = tid;
    float s = 0.f;
    if (k < D_NODE)
        for (int q = 0; q < D_HID; ++q)
            s = fmaf(wrow[q], Wm[q*D_NODE + k], s);
    wout[k] = f2bf(k < D_NODE ? s : 0.f);

    __shared__ float red[128];
    float p = 0.f;
    for (int q = tid; q < D_HID; q += 128) p = fmaf(bm[q], wrow[q], p);
    red[tid] = p;
    __syncthreads();
    for (int off = 64; off > 0; off >>= 1) {
        if (tid < off) red[tid] += red[tid + off];
        __syncthreads();
    }
    if (tid == 0) {
        float base = bih[g*D_HID + j] + red[0];
        if (g < 2) base += bhh[g*D_HID + j];
        bc[(dir*3+g)*320 + j] = base;
        if (g == 2) bhhn[dir*320 + j] = bhh[2*D_HID + j];
    }
}

// ---------------- KAW: gather+mean -> Abf; nodes -> Nbf; Wout/Wnode -> bf16 ----------------
// blocks 0..383: Abf/Nbf ; blocks 384..1455: Woutbf (dir-interleaved k: dir*304+jj) + Wnbf
__global__ __launch_bounds__(256)
void kAW(const float* __restrict__ nodes, const int* __restrict__ trip,
         const float* __restrict__ Wout, const float* __restrict__ Wnode,
         u32* __restrict__ Abf, u32* __restrict__ Nbf,
         u16* __restrict__ Woutbf, u16* __restrict__ Wnbf)
{
    int blk = blockIdx.x;
    if (blk < 384) {
        int gid = blk*256 + threadIdx.x;
        if (gid < 65536) {
            int b = gid >> 9;
            int hidx = trip[(size_t)gid*3];
            int tidx = trip[(size_t)gid*3 + 2];
            const float4* nh = (const float4*)(nodes + ((size_t)b*NNODE + hidx)*D_NODE);
            const float4* nt = (const float4*)(nodes + ((size_t)b*NNODE + tidx)*D_NODE);
            u32* ar = Abf + (size_t)gid*64;
            #pragma unroll 5
            for (int i = 0; i < 25; ++i) {
                float4 a = nh[i], c = nt[i];
                ar[i*2]   = pack_bf(0.5f*(a.x+c.x), 0.5f*(a.y+c.y));
                ar[i*2+1] = pack_bf(0.5f*(a.z+c.z), 0.5f*(a.w+c.w));
            }
            #pragma unroll
            for (int i = 50; i < 64; ++i) ar[i] = 0;
        } else {
            int r = gid - 65536;
            const float4* nr = (const float4*)(nodes + (size_t)r*D_NODE);
            u32* ar = Nbf + (size_t)r*64;
            #pragma unroll 5
            for (int i = 0; i < 25; ++i) {
                float4 a = nr[i];
                ar[i*2]   = pack_bf(a.x, a.y);
                ar[i*2+1] = pack_bf(a.z, a.w);
            }
            #pragma unroll
            for (int i = 50; i < 64; ++i) ar[i] = 0;
        }
    } else {
        int idx = (blk - 384)*256 + threadIdx.x;
        if (idx < 384*608) {
            int j = idx / 608, k = idx % 608;
            int d = k / 304, jj = k - d*304;
            float v = (j < D_HID && jj < D_HID) ? Wout[(size_t)j*600 + d*D_HID + jj] : 0.f;
            Woutbf[idx] = f2bf(v);
        } else {
            int i2 = idx - 384*608;
            if (i2 < 320*128) {
                int j = i2 >> 7, k = i2 & 127;
                float v = (j < D_HID && k < D_NODE) ? Wnode[(size_t)j*D_NODE + k] : 0.f;
                Wnbf[i2] = f2bf(v);
            }
        }
    }
}

// ---------------- KC: ctx -> bf16 padded [32768][320] (runs after k2; lives in dead H region) ----------------
__global__ __launch_bounds__(256)
void kC(const float* __restrict__ ctx, u32* __restrict__ Cbf)
{
    int idx = blockIdx.x*256 + threadIdx.x;     // over 32768*160 u32
    int r = idx / 160, cp = idx % 160;
    int col = cp*2;
    u32 v = 0;
    if (col < D_HID) {
        float2 f = *(const float2*)(ctx + (size_t)r*D_HID + col);
        v = pack_bf(f.x, f.y);
    }
    Cbf[(size_t)r*160 + cp] = v;
}

// ---------------- K1: MFMA GEMM + GRU epilogue -> H[M][608] bf16 (col = dir*304 + j) ----------------
// grid (512, 10): 128 rows/block; wave w -> 16 j (j0w = jg*64 + w*16), 3 gates.
__global__ __launch_bounds__(256, 2)
void k1_gru(const u16* __restrict__ Abf, const u16* __restrict__ W4bf,
            const float* __restrict__ bc, const float* __restrict__ bhhn,
            u16* __restrict__ H)
{
    __shared__ char smem[32768];   // A frags [8 ms][4 ks][64][16B]; reused as transpose buf
    int tid = threadIdx.x;
    int lane = tid & 63, w = tid >> 6;
    int l15 = lane & 15, lq = lane >> 4;
    int m0 = blockIdx.x * 128;
    int dir = blockIdx.y / 5;
    int jg = blockIdx.y % 5;
    int j0w = jg*64 + w*16;        // 0..304

    bf16x8 bfr[3][4];
    const u16* Wb = W4bf + (size_t)dir*3*320*128;
    #pragma unroll
    for (int g = 0; g < 3; ++g)
        #pragma unroll
        for (int ks = 0; ks < 4; ++ks)
            bfr[g][ks] = *(const bf16x8*)(Wb + ((size_t)(g*320 + j0w + l15))*128 + ks*32 + lq*8);

    // stage A (128 rows x 128 k): wave w stages msub {w, w+4}
    #pragma unroll
    for (int mi = 0; mi < 2; ++mi) {
        int ms = w + mi*4;
        #pragma unroll
        for (int ks = 0; ks < 4; ++ks)
            gload_lds16(Abf + ((size_t)(m0 + ms*16 + l15))*128 + ks*32 + lq*8,
                        smem + (size_t)((ms*4 + ks)*64)*16);
    }
    __syncthreads();

    f32x4 acc[8][3];
    #pragma unroll
    for (int ms = 0; ms < 8; ++ms)
        #pragma unroll
        for (int g = 0; g < 3; ++g)
            acc[ms][g] = (f32x4){0.f,0.f,0.f,0.f};

    #pragma unroll
    for (int ms = 0; ms < 8; ++ms)
        #pragma unroll
        for (int ks = 0; ks < 4; ++ks) {
            bf16x8 a = *(const bf16x8*)(smem + (size_t)(((ms*4+ks)*64 + lane))*16);
            acc[ms][0] = __builtin_amdgcn_mfma_f32_16x16x32_bf16(a, bfr[0][ks], acc[ms][0], 0,0,0);
            acc[ms][1] = __builtin_amdgcn_mfma_f32_16x16x32_bf16(a, bfr[1][ks], acc[ms][1], 0,0,0);
            acc[ms][2] = __builtin_amdgcn_mfma_f32_16x16x32_bf16(a, bfr[2][ks], acc[ms][2], 0,0,0);
        }

    int j = j0w + l15;             // <= 319; pad j has zero W/biases -> h = 0
    float bcr = bc[(dir*3+0)*320 + j];
    float bcz = bc[(dir*3+1)*320 + j];
    float bcn = bc[(dir*3+2)*320 + j];
    float bn2 = bhhn[dir*320 + j];

    __syncthreads();               // all waves done reading A frags; reuse smem
    u16* lt = (u16*)smem + w*128*24;   // [128 rows][24 u16] per wave (48B rows, 16B aligned)
    #pragma unroll
    for (int ms = 0; ms < 8; ++ms)
        #pragma unroll
        for (int i = 0; i < 4; ++i) {
            float r = fsig(acc[ms][0][i] + bcr);
            float z = fsig(acc[ms][1][i] + bcz);
            float n = ftanh(acc[ms][2][i] + bcn + r*bn2);
            float h = (1.f - z)*n;
            lt[(ms*16 + lq*4 + i)*24 + l15] = f2bf(h);
        }
    // wave-internal DS ordering -> no barrier needed before readback
    if (j0w < 304) {
        #pragma unroll
        for (int half = 0; half < 2; ++half) {
            int r = half*64 + lane;
            uint4 v0 = *(const uint4*)(lt + r*24);
            uint4 v1 = *(const uint4*)(lt + r*24 + 8);
            u16* dst = H + (size_t)(m0 + r)*608 + dir*304 + j0w;
            *(uint4*)dst = v0;
            *(uint4*)(dst + 8) = v1;
        }
    }
}

// ---------------- K2: Hid = tanh(H @ Wout^T + bout) via MFMA -> bf16 [M][320] (zero-padded) ----------------
__global__ __launch_bounds__(256, 2)
void k2_out(const u16* __restrict__ H, const u16* __restrict__ Woutbf,
            const float* __restrict__ bout, u16* __restrict__ Hid)
{
    __shared__ char smem[40960];
    int tid = threadIdx.x;
    int lane = tid & 63, w = tid >> 6;
    int l15 = lane & 15, lq = lane >> 4;
    int m0 = blockIdx.x * 64;
    int j0 = blockIdx.y * 128;
    int jA = j0 + w*16, jB = j0 + 64 + w*16;

    bf16x8 bA[19], bB[19];
    #pragma unroll
    for (int ks = 0; ks < 19; ++ks) {
        bA[ks] = *(const bf16x8*)(Woutbf + ((size_t)(jA + l15))*608 + ks*32 + lq*8);
        bB[ks] = *(const bf16x8*)(Woutbf + ((size_t)(jB + l15))*608 + ks*32 + lq*8);
    }
    f32x4 acc[4][2];
    #pragma unroll
    for (int ms = 0; ms < 4; ++ms) { acc[ms][0] = (f32x4){0,0,0,0}; acc[ms][1] = (f32x4){0,0,0,0}; }

    #pragma unroll
    for (int c = 0; c < 2; ++c) {
        const int kb = c ? 10 : 0;
        const int nks = c ? 9 : 10;
        #pragma unroll
        for (int kk = 0; kk < 10; ++kk)
            if (kk < nks) {
                const u16* g = H + ((size_t)(m0 + w*16 + l15))*608 + (kb+kk)*32 + lq*8;
                gload_lds16(g, smem + (size_t)((w*10 + kk)*64)*16);
            }
        __syncthreads();
        #pragma unroll
        for (int ms = 0; ms < 4; ++ms)
            #pragma unroll
            for (int kk = 0; kk < 10; ++kk)
                if (kk < nks) {
                    bf16x8 a = *(const bf16x8*)(smem + (size_t)(((ms*10+kk)*64 + lane))*16);
                    acc[ms][0] = __builtin_amdgcn_mfma_f32_16x16x32_bf16(a, bA[kb+kk], acc[ms][0], 0,0,0);
                    acc[ms][1] = __builtin_amdgcn_mfma_f32_16x16x32_bf16(a, bB[kb+kk], acc[ms][1], 0,0,0);
                }
        __syncthreads();
    }

    u16* lt = (u16*)smem + w*64*24;   // [64 rows][24 u16] per wave
    #pragma unroll
    for (int jj = 0; jj < 2; ++jj) {
        int jX = jj ? jB : jA;
        if (jX >= 320) continue;       // wave-uniform
        int j = jX + l15;
        bool real = (j < D_HID);
        float bo = real ? bout[j] : 0.f;
        #pragma unroll
        for (int ms = 0; ms < 4; ++ms)
            #pragma unroll
            for (int i = 0; i < 4; ++i) {
                float v = real ? ftanh(acc[ms][jj][i] + bo) : 0.f;
                lt[(ms*16 + lq*4 + i)*24 + l15] = f2bf(v);
            }
        int r = lane;
        uint4 v0 = *(const uint4*)(lt + r*24);
        uint4 v1 = *(const uint4*)(lt + r*24 + 8);
        u16* dst = Hid + (size_t)(m0 + r)*320 + jX;
        *(uint4*)dst = v0;
        *(uint4*)(dst + 8) = v1;
    }
}

// ---------------- K3: fused scores + softmax + partial-alpha + partial-rep ----------------
// grid (4, 128): block = 64 queries (m) x all 512 t, K=320. Scores live in VGPRs.
__global__ __launch_bounds__(256, 2)
void k3_attn(const u16* __restrict__ Cbf, const u16* __restrict__ Hid,
             float* __restrict__ repp)
{
    __shared__ char smemA[4096];       // 4 m-groups x 64 x 16 B
    __shared__ char smemB[32768];      // 32 t-groups x 64 x 16 B
    __shared__ float rmax[64*4], rsum[64*4];
    __shared__ float csa[512];
    int tid = threadIdx.x;
    int lane = tid & 63, w = tid >> 6;
    int l15 = lane & 15, lq = lane >> 4;
    int b = blockIdx.y;
    int mblk = blockIdx.x;
    const u16* Ab = Cbf + ((size_t)b*LQn + mblk*64)*320;
    const u16* Bb = Hid + ((size_t)b*TSEQ)*320;

    f32x4 acc[4][8];   // [m-group][t-group(of wave)] ; t = w*128 + g*16 + l15, row = ms*16+lq*4+i
    #pragma unroll
    for (int ms = 0; ms < 4; ++ms)
        #pragma unroll
        for (int g = 0; g < 8; ++g)
            acc[ms][g] = (f32x4){0,0,0,0};

    for (int ks = 0; ks < 10; ++ks) {
        gload_lds16(Ab + ((size_t)(w*16 + l15))*320 + ks*32 + lq*8,
                    smemA + (size_t)(w*64)*16);
        #pragma unroll
        for (int i = 0; i < 8; ++i) {
            int nt = w*8 + i;
            gload_lds16(Bb + ((size_t)(nt*16 + l15))*320 + ks*32 + lq*8,
                        smemB + (size_t)(nt*64)*16);
        }
        __syncthreads();
        bf16x8 afr[4];
        #pragma unroll
        for (int ms = 0; ms < 4; ++ms)
            afr[ms] = *(const bf16x8*)(smemA + (size_t)((ms*64 + lane))*16);
        #pragma unroll
        for (int i = 0; i < 8; ++i) {
            bf16x8 bfr = *(const bf16x8*)(smemB + (size_t)(((w*8+i)*64 + lane))*16);
            #pragma unroll
            for (int ms = 0; ms < 4; ++ms)
                acc[ms][i] = __builtin_amdgcn_mfma_f32_16x16x32_bf16(afr[ms], bfr, acc[ms][i], 0,0,0);
        }
        __syncthreads();
    }

    // ---- row max (cross-wave via LDS) ----
    #pragma unroll
    for (int ms = 0; ms < 4; ++ms)
        #pragma unroll
        for (int i = 0; i < 4; ++i) {
            float m = acc[ms][0][i];
            #pragma unroll
            for (int g = 1; g < 8; ++g) m = fmaxf(m, acc[ms][g][i]);
            m = fmaxf(m, __shfl_xor(m, 1));
            m = fmaxf(m, __shfl_xor(m, 2));
            m = fmaxf(m, __shfl_xor(m, 4));
            m = fmaxf(m, __shfl_xor(m, 8));
            if (l15 == 0) rmax[(ms*16 + lq*4 + i)*4 + w] = m;
        }
    __syncthreads();
    float mfin[4][4];
    #pragma unroll
    for (int ms = 0; ms < 4; ++ms)
        #pragma unroll
        for (int i = 0; i < 4; ++i) {
            float4 mv = *(const float4*)&rmax[(ms*16 + lq*4 + i)*4];
            mfin[ms][i] = fmaxf(fmaxf(mv.x, mv.y), fmaxf(mv.z, mv.w));
        }
    // ---- exp in place + row sum ----
    #pragma unroll
    for (int ms = 0; ms < 4; ++ms)
        #pragma unroll
        for (int i = 0; i < 4; ++i) {
            float s = 0.f;
            #pragma unroll
            for (int g = 0; g < 8; ++g) {
                float e = __expf(acc[ms][g][i] - mfin[ms][i]);
                acc[ms][g][i] = e;
                s += e;
            }
            s += __shfl_xor(s, 1);
            s += __shfl_xor(s, 2);
            s += __shfl_xor(s, 4);
            s += __shfl_xor(s, 8);
            if (l15 == 0) rsum[(ms*16 + lq*4 + i)*4 + w] = s;
        }
    __syncthreads();
    float inv[4][4];
    #pragma unroll
    for (int ms = 0; ms < 4; ++ms)
        #pragma unroll
        for (int i = 0; i < 4; ++i) {
            float4 sv = *(const float4*)&rsum[(ms*16 + lq*4 + i)*4];
            inv[ms][i] = __builtin_amdgcn_rcpf(sv.x + sv.y + sv.z + sv.w);
        }
    // ---- column sums over this block's 64 rows -> csa[t] ----
    #pragma unroll
    for (int g = 0; g < 8; ++g) {
        float c = 0.f;
        #pragma unroll
        for (int ms = 0; ms < 4; ++ms)
            #pragma unroll
            for (int i = 0; i < 4; ++i)
                c = fmaf(acc[ms][g][i], inv[ms][i], c);
        c += __shfl_xor(c, 16);
        c += __shfl_xor(c, 32);
        if (lq == 0) csa[w*128 + g*16 + l15] = c;
    }
    __syncthreads();
    // ---- partial rep: rep_p[j] = sum_t csa[t] * Hid[b][t][j] ----
    float* rp = repp + ((size_t)b*4 + mblk)*320;
    for (int j = tid; j < 320; j += 256) {
        const u16* hp = Bb + j;
        float a = 0.f;
        #pragma unroll 8
        for (int t = 0; t < TSEQ; ++t)
            a = fmaf(csa[t], bf2f(hp[(size_t)t*320]), a);
        rp[j] = a;
    }
}

// ---------------- K4: sum 4 partial reps ; layernorm -> path_feature ----------------
__global__ __launch_bounds__(320)
void k4_rep(const float* __restrict__ repp,
            const float* __restrict__ gamma, const float* __restrict__ beta,
            float* __restrict__ outP)
{
    __shared__ float rs[5], rss[5];
    int tid = threadIdx.x, b = blockIdx.x;
    const float* rp = repp + (size_t)b*4*320;
    float acc = 0.f;
    if (tid < D_HID)
        acc = rp[tid] + rp[320 + tid] + rp[640 + tid] + rp[960 + tid];
    float v = (tid < D_HID) ? acc : 0.f;
    float s = v, q = v*v;
    #pragma unroll
    for (int off = 32; off > 0; off >>= 1) { s += __shfl_xor(s, off, 64); q += __shfl_xor(q, off, 64); }
    if ((tid & 63) == 0) { rs[tid >> 6] = s; rss[tid >> 6] = q; }
    __syncthreads();
    float S = rs[0]+rs[1]+rs[2]+rs[3]+rs[4];
    float Q = rss[0]+rss[1]+rss[2]+rss[3]+rss[4];
    float mu = S * (1.f/300.f);
    float var = Q * (1.f/300.f) - mu*mu;
    if (tid < D_HID)
        outP[(size_t)b*D_HID + tid] = (acc - mu) * rsqrtf(var + 1e-5f) * gamma[tid] + beta[tid];
}

// ---------------- K5: node_feature = nodes @ Wnode^T + bnode via MFMA (fp32 out) ----------------
__global__ __launch_bounds__(256)
void k5_node(const u16* __restrict__ Nbf, const u16* __restrict__ Wnbf,
             const float* __restrict__ bn, float* __restrict__ outN)
{
    __shared__ char smem[16384];
    int tid = threadIdx.x;
    int lane = tid & 63, w = tid >> 6;
    int l15 = lane & 15, lq = lane >> 4;
    int m0 = blockIdx.x * 64;
    int j0w = blockIdx.y*64 + w*16;

    bf16x8 bw[4];
    #pragma unroll
    for (int ks = 0; ks < 4; ++ks)
        bw[ks] = *(const bf16x8*)(Wnbf + ((size_t)(j0w + l15))*128 + ks*32 + lq*8);

    #pragma unroll
    for (int ks = 0; ks < 4; ++ks) {
        const u16* g = Nbf + ((size_t)(m0 + w*16 + l15))*128 + ks*32 + lq*8;
        gload_lds16(g, smem + (size_t)((w*4 + ks)*64)*16);
    }
    __syncthreads();

    f32x4 acc[4];
    #pragma unroll
    for (int ms = 0; ms < 4; ++ms) acc[ms] = (f32x4){0,0,0,0};
    #pragma unroll
    for (int ms = 0; ms < 4; ++ms)
        #pragma unroll
        for (int ks = 0; ks < 4; ++ks) {
            bf16x8 a = *(const bf16x8*)(smem + (size_t)(((ms*4+ks)*64 + lane))*16);
            acc[ms] = __builtin_amdgcn_mfma_f32_16x16x32_bf16(a, bw[ks], acc[ms], 0,0,0);
        }

    int j = j0w + l15;
    if (j < D_HID) {
        float bo = bn[j];
        #pragma unroll
        for (int ms = 0; ms < 4; ++ms)
            #pragma unroll
            for (int i = 0; i < 4; ++i)
                outN[(size_t)(m0 + ms*16 + lq*4 + i)*D_HID + j] = acc[ms][i] + bo;
    }
}

extern "C" void kernel_launch(void* const* d_in, const int* in_sizes, int n_in,
                              void* d_out, int out_size, void* d_ws, size_t ws_size,
                              hipStream_t stream) {
    const float* nodes  = (const float*)d_in[0];
    const float* ctx    = (const float*)d_in[1];
    const int*   trip   = (const int*)d_in[2];
    const float* Wm     = (const float*)d_in[4];
    const float* bm     = (const float*)d_in[5];
    const float* Wihf   = (const float*)d_in[6];
    const float* bihf   = (const float*)d_in[7];
    const float* bhhf   = (const float*)d_in[8];
    const float* Wihb   = (const float*)d_in[9];
    const float* bihb   = (const float*)d_in[10];
    const float* bhhb   = (const float*)d_in[11];
    const float* Wout   = (const float*)d_in[12];
    const float* bout   = (const float*)d_in[13];
    const float* Wnode  = (const float*)d_in[14];
    const float* bnode  = (const float*)d_in[15];
    const float* gamma  = (const float*)d_in[16];
    const float* beta   = (const float*)d_in[17];
    float* out = (float*)d_out;

    char* ws = (char*)d_ws;
    u16*   W4bf   = (u16*)(ws);                         // 491,520 B
    u16*   Woutbf = (u16*)(ws + 491520);                // 466,944 B
    u16*   Wnbf   = (u16*)(ws + 958464);                //  81,920 B
    float* bc     = (float*)(ws + 1040384);             //   7,680 B
    float* bhhn   = (float*)(ws + 1048064);             //   2,560 B
    char*  Hbase  = ws + 1050624;
    u16*   H      = (u16*)Hbase;                        // 79,691,776 B  [65536][608] (col = dir*304+j)
    u32*   Cbf    = (u32*)(Hbase + 33554432ull);        // overlay (after k2): 20,971,520 B
    char*  hidbase = Hbase + 79691776ull;               // 80,742,400
    u16*   Hid    = (u16*)hidbase;                      // 41,943,040 B  [65536][320]
    u32*   Abf    = (u32*)hidbase;                      // overlay: 16,777,216 B (dead before k2)
    u32*   Nbf    = (u32*)(hidbase + 16777216ull);      // overlay:  8,388,608 B (dead before k2)
    float* repp   = (float*)(ws + 122685440ull);        // 655,360 B -> total <= 123,734,016 B

    k0_prep<<<dim3(320,3,2), 128, 0, stream>>>(Wm,bm,Wihf,bihf,bhhf,Wihb,bihb,bhhb,W4bf,bc,bhhn);
    kAW    <<<1456, 256, 0, stream>>>(nodes,trip,Wout,Wnode,Abf,Nbf,Woutbf,Wnbf);
    k1_gru <<<dim3(512,10),  256, 0, stream>>>((const u16*)Abf,W4bf,bc,bhhn,H);
    k5_node<<<dim3(512,5),   256, 0, stream>>>((const u16*)Nbf,Wnbf,bnode,out + 38400);   // before k2 (overlay!)
    k2_out <<<dim3(1024,3),  256, 0, stream>>>(H,Woutbf,bout,Hid);
    kC     <<<20480, 256, 0, stream>>>(ctx, Cbf);                                          // after k2 (overlay!)
    k3_attn<<<dim3(4,128),   256, 0, stream>>>((const u16*)Cbf, Hid, repp);
    k4_rep <<<128,           320, 0, stream>>>(repp,gamma,beta,out);
    hipMemsetAsync(out + 38400 + 9830400, 0, 32768*sizeof(float), stream);
}